// Round 1
// baseline (230.114 us; speedup 1.0000x reference)
//
#include <hip/hip_runtime.h>
#include <hip/hip_bf16.h>

// Correlation (FlowNet): out[b, 21*ky+kx, i, j] = (1/C) sum_c in1[b,c,i,j] * in2[b,c,i+2ky-20,j+2kx-20]
// Parity split j=2u+pj -> banded Gram G[u,w]=sum_c X[c,u]Y[c,w], band w=u+kx-10, via bf16 MFMA.

#define NB 8
#define NC 256
#define NH 96
#define NW 128
#define NU 64
#define ND 21
#define NK 441

typedef __attribute__((ext_vector_type(8))) short s16x8;
typedef __attribute__((ext_vector_type(4))) float f32x4;

__device__ __forceinline__ unsigned short f2bf(float f) {
    unsigned int x = __float_as_uint(f);
    x += 0x7fffu + ((x >> 16) & 1u);   // RTNE
    return (unsigned short)(x >> 16);
}

// ---------------- prepass: fp32 [b][c][i][j] -> bf16 [b][pj][i][u][c] (both inputs)
__global__ __launch_bounds__(256) void repack_kernel(
    const float* __restrict__ in1, const float* __restrict__ in2,
    unsigned short* __restrict__ xg, unsigned short* __restrict__ yg)
{
    int bid = blockIdx.x;
    int src = bid & 1;
    int ct  = (bid >> 1) & 3;          // c-tile of 64
    int rest = bid >> 3;
    int i = rest % NH;
    int b = rest / NH;
    const float* in = src ? in2 : in1;
    unsigned short* og = src ? yg : xg;
    int c0 = ct * 64;

    __shared__ unsigned short tbuf[128][68];   // [j][c_local], +4 pad kills bank conflicts

    int tid = threadIdx.x;
    int j  = tid & 127;
    int ch = tid >> 7;                 // 0..1
    #pragma unroll 4
    for (int p = 0; p < 32; ++p) {
        int cl = p * 2 + ch;
        float v = in[(((size_t)b * NC + (c0 + cl)) * NH + i) * NW + j];
        tbuf[j][cl] = f2bf(v);
    }
    __syncthreads();
    int c2 = tid & 31;                 // c-pair
    int jr = tid >> 5;                 // 0..7
    #pragma unroll
    for (int jj0 = 0; jj0 < 128; jj0 += 8) {
        int jj = jj0 + jr;
        int pj = jj & 1, u = jj >> 1;
        unsigned int val = *reinterpret_cast<const unsigned int*>(&tbuf[jj][2 * c2]);
        size_t o = ((((size_t)b * 2 + pj) * NH + i) * NU + u) * NC + c0 + 2 * c2;
        *reinterpret_cast<unsigned int*>(&og[o]) = val;
    }
}

// ---------------- main kernel ----------------
// LDS: X[2pj][64u][256c] bf16 (swizzled) | Y same | G[2pj][4t][16m][50] f32 | 16B zero
#define XOFF 0
#define YOFF 65536
#define GOFF 131072
#define GPITCH 50
#define ZOFF (GOFF + 2 * 4 * 16 * GPITCH * 4)   // 156672
#define LDSZ (ZOFF + 16)

__global__ __launch_bounds__(512) void corr_kernel(
    const unsigned short* __restrict__ xg,
    const unsigned short* __restrict__ yg,
    float* __restrict__ out)
{
    __shared__ __align__(16) unsigned char LDS[LDSZ];

    int bid = blockIdx.x;
    int i = bid % NH;
    int b = bid / NH;
    int tid = threadIdx.x;
    int lane = tid & 63;
    int wv = tid >> 6;        // 8 waves
    int pj = wv >> 2;         // wave's parity
    int tt = wv & 3;          // wave's u-tile

    if (tid == 0) {
        uint4 z = {0u, 0u, 0u, 0u};
        *reinterpret_cast<uint4*>(&LDS[ZOFF]) = z;
    }

    // stage X (both parities, resident across all ky)
    {
        const uint4* src = reinterpret_cast<const uint4*>(xg);
        #pragma unroll
        for (int it = 0; it < 8; ++it) {
            int g = it * 512 + tid;
            int p = g >> 11;
            int rem = g & 2047;
            int u = rem >> 5, off = rem & 31;
            uint4 v = src[(((size_t)(b * 2 + p) * NH + i) * NU + u) * 32 + off];
            int lb = XOFF + (p << 15) + ((u * 512 + off * 16) ^ ((u & 7) << 4));
            *reinterpret_cast<uint4*>(&LDS[lb]) = v;
        }
    }

    const int m  = lane & 15;   // MFMA row/col-within-16
    const int kq = lane >> 4;   // c-quad
    const int u  = tt * 16 + m;
    const int xrow = XOFF + (pj << 15) + u * 512;
    const int xsw  = (u & 7) << 4;

    // B-operand row bases for the wave's 3 w-tiles (ky-invariant)
    int yb0, yb1, yb2, sw0, sw1, sw2;
    {
        int w0 = tt * 16 - 10 + m;
        int w1 = w0 + 16;
        int w2 = w0 + 32;
        yb0 = (w0 >= 0 && w0 < NU) ? (YOFF + (pj << 15) + w0 * 512) : -1;
        yb1 = (w1 >= 0 && w1 < NU) ? (YOFF + (pj << 15) + w1 * 512) : -1;
        yb2 = (w2 >= 0 && w2 < NU) ? (YOFF + (pj << 15) + w2 * 512) : -1;
        sw0 = (w0 & 7) << 4;
        sw1 = (w1 & 7) << 4;
        sw2 = (w2 & 7) << 4;
    }

    const float inv = 1.0f / 256.0f;

    for (int ky = 0; ky < ND; ++ky) {
        int r = i + 2 * ky - 20;
        bool valid = (r >= 0) && (r < NH);
        size_t obase = (((size_t)b * NK + 21 * ky) * NH + i) * NW + (tid & 127);

        if (valid) {
            // stage Y row r (both parities)
            const uint4* src = reinterpret_cast<const uint4*>(yg);
            #pragma unroll
            for (int it = 0; it < 8; ++it) {
                int g = it * 512 + tid;
                int p = g >> 11;
                int rem = g & 2047;
                int uu = rem >> 5, off = rem & 31;
                uint4 v = src[(((size_t)(b * 2 + p) * NH + r) * NU + uu) * 32 + off];
                int lb = YOFF + (p << 15) + ((uu * 512 + off * 16) ^ ((uu & 7) << 4));
                *reinterpret_cast<uint4*>(&LDS[lb]) = v;
            }
            __syncthreads();

            f32x4 acc0 = {0.f, 0.f, 0.f, 0.f};
            f32x4 acc1 = {0.f, 0.f, 0.f, 0.f};
            f32x4 acc2 = {0.f, 0.f, 0.f, 0.f};
            #pragma unroll
            for (int ks = 0; ks < 8; ++ks) {
                int c2 = (ks * 32 + kq * 8) * 2;   // byte offset within row
                s16x8 af = *reinterpret_cast<const s16x8*>(&LDS[xrow + (c2 ^ xsw)]);
                int a0 = (yb0 < 0) ? ZOFF : (yb0 + (c2 ^ sw0));
                s16x8 bf0 = *reinterpret_cast<const s16x8*>(&LDS[a0]);
                acc0 = __builtin_amdgcn_mfma_f32_16x16x32_bf16(af, bf0, acc0, 0, 0, 0);
                int a1 = (yb1 < 0) ? ZOFF : (yb1 + (c2 ^ sw1));
                s16x8 bf1 = *reinterpret_cast<const s16x8*>(&LDS[a1]);
                acc1 = __builtin_amdgcn_mfma_f32_16x16x32_bf16(af, bf1, acc1, 0, 0, 0);
                int a2 = (yb2 < 0) ? ZOFF : (yb2 + (c2 ^ sw2));
                s16x8 bf2 = *reinterpret_cast<const s16x8*>(&LDS[a2]);
                acc2 = __builtin_amdgcn_mfma_f32_16x16x32_bf16(af, bf2, acc2, 0, 0, 0);
            }

            // spill G tiles to LDS: D[row=4*kq+v][col=lane&15] per verified C/D layout
            int gb = GOFF + wv * (16 * GPITCH * 4);
            #pragma unroll
            for (int v4 = 0; v4 < 4; ++v4) {
                float* gr = reinterpret_cast<float*>(&LDS[gb + (kq * 4 + v4) * (GPITCH * 4)]);
                gr[m]      = acc0[v4];
                gr[16 + m] = acc1[v4];
                gr[32 + m] = acc2[v4];
            }
            __syncthreads();

            // band extraction + coalesced store: G col within wave's 48 = (u&15) + kx
            int j = tid & 127;
            int uo = j >> 1;
            int mo = uo & 15;
            const float* grow = reinterpret_cast<const float*>(
                &LDS[GOFF + (((j & 1) * 4 + (uo >> 4)) * 16 + mo) * (GPITCH * 4)]);
            for (int kx = tid >> 7; kx < ND; kx += 4) {
                out[obase + (size_t)kx * (NH * NW)] = grow[mo + kx] * inv;
            }
        } else {
            for (int kx = tid >> 7; kx < ND; kx += 4) {
                out[obase + (size_t)kx * (NH * NW)] = 0.0f;
            }
        }
    }
}

// ---------------- fallback (ws too small): 1 thread per output ----------------
__global__ __launch_bounds__(256) void corr_naive(
    const float* __restrict__ in1, const float* __restrict__ in2, float* __restrict__ out)
{
    size_t o = (size_t)blockIdx.x * 256 + threadIdx.x;
    if (o >= (size_t)NB * NK * NH * NW) return;
    int j = o & 127;
    int i = (int)((o >> 7) % NH);
    size_t rest = o / ((size_t)NH * NW);
    int k = (int)(rest % NK);
    int b = (int)(rest / NK);
    int ky = k / ND, kx = k % ND;
    int r = i + 2 * ky - 20, jc = j + 2 * kx - 20;
    float s = 0.f;
    if (r >= 0 && r < NH && jc >= 0 && jc < NW) {
        const float* p1 = in1 + (((size_t)b * NC) * NH + i) * NW + j;
        const float* p2 = in2 + (((size_t)b * NC) * NH + r) * NW + jc;
        for (int c = 0; c < NC; ++c) { s += p1[0] * p2[0]; p1 += NH * NW; p2 += NH * NW; }
    }
    out[o] = s * (1.0f / 256.0f);
}

extern "C" void kernel_launch(void* const* d_in, const int* in_sizes, int n_in,
                              void* d_out, int out_size, void* d_ws, size_t ws_size,
                              hipStream_t stream) {
    const float* in1 = (const float*)d_in[0];
    const float* in2 = (const float*)d_in[1];
    float* out = (float*)d_out;

    const size_t elems_per_input = (size_t)NB * 2 * NH * NU * NC;   // 25,165,824
    const size_t need = 2 * elems_per_input * sizeof(unsigned short); // ~100.7 MB

    if (ws_size < need) {
        size_t total = (size_t)NB * NK * NH * NW;
        corr_naive<<<(int)((total + 255) / 256), 256, 0, stream>>>(in1, in2, out);
        return;
    }

    unsigned short* xg = (unsigned short*)d_ws;
    unsigned short* yg = xg + elems_per_input;

    repack_kernel<<<NB * NH * 4 * 2, 256, 0, stream>>>(in1, in2, xg, yg);
    corr_kernel<<<NB * NH, 512, 0, stream>>>(xg, yg, out);
}